// Round 11
// baseline (125.743 us; speedup 1.0000x reference)
//
#include <hip/hip_runtime.h>
#include <math.h>

#define TPB 256
constexpr int Bn = 64;
constexpr int Ln = 262144;          // 2^18
constexpr int S  = 2048;            // chunk/tile size
constexpr int NC = Ln / S;          // 128 chunks per row
constexpr int HA = S + 301;         // halo'd extent (2349)
constexpr int EPT = 11;             // segment length; ODD stride -> conflict-free LDS
constexpr int OPT = S / TPB;        // 8 outputs per thread
constexpr int NP = 1280;            // float2 pairs staged (2560 floats, li in [-1,2559))
constexpr int LDSZ = 2820;          // 1 (shift) + 11*256=2816 coverage + pad

constexpr float TWO_PI_F = 6.28318530717958647692f;
constexpr float PI_F = 3.14159265358979323846f;
constexpr float HALF_PI_F = 1.57079632679489661923f;
constexpr float INV_TWO_PI_F = 0.15915494309189533577f;

// wrap count: k = floor((d+pi)/(2pi)), with the reference's dm==-pi & d>0 fixup.
// For |d| <= pi (one side zero-padded) returns 0 automatically.
__device__ __forceinline__ int wrap_k(float d) {
    float kf = floorf(__fmaf_rn(d, INV_TWO_PI_F, 0.5f));
    float dm = __fmaf_rn(-kf, TWO_PI_F, d);
    if (dm == -PI_F && d > 0.f) kf -= 1.f;
    return (int)kf;
}

// polynomial atan2, abs err ~2e-7 rad
__device__ __forceinline__ float fast_atan2f(float q, float i) {
    float aq = fabsf(q), ai = fabsf(i);
    float mx = fmaxf(aq, ai), mn = fminf(aq, ai);
    float r = __builtin_amdgcn_rcpf(mx);
    r = r * (2.0f - mx * r);                 // one NR step
    float t = mn * r;                        // in [0, 1+eps]
    if (mx == 0.f) t = 0.f;                  // atan2(0,0) -> 0
    float s = t * t;
    float p = __fmaf_rn(s, 0.0028662257f, -0.0161657367f);
    p = __fmaf_rn(p, s,  0.0429096138f);
    p = __fmaf_rn(p, s, -0.0752896400f);
    p = __fmaf_rn(p, s,  0.1065626393f);
    p = __fmaf_rn(p, s, -0.1420889944f);
    p = __fmaf_rn(p, s,  0.1999355085f);
    p = __fmaf_rn(p, s, -0.3333314528f);
    float at = __fmaf_rn(p * s, t, t);       // t + t*s*poly
    if (aq > ai) at = HALF_PI_F - at;
    if (i < 0.f) at = PI_F - at;
    return (q < 0.f) ? -at : at;
}

// K1: locally-anchored unwrap + moving-average high-pass (2*pi row offset
// cancels in x - avg; row-end pad windows fixed by k_post).
__global__ __launch_bounds__(TPB, 7) void k_filt(const float* __restrict__ Ig,
                                                 const float* __restrict__ Qg,
                                                 int* __restrict__ Ag,     // local scan at g=t0-1
                                                 int* __restrict__ Bg,     // local scan at g=t0+S-1
                                                 float* __restrict__ out,
                                                 float* __restrict__ PS) {
    __shared__ __align__(16) float spu_s[LDSZ];   // phase -> pu -> prefix(pu)
    __shared__ __align__(16) float smg_s[LDSZ];   // magnitude -> prefix(magnitude)
    __shared__ int iwt[TPB / 64];
    __shared__ float fwt[TPB / 64];
    __shared__ double rbuf[TPB / 64][4];
    float* spu = spu_s + 1;             // logical li -> spu[li]
    float* smg = smg_s + 1;

    const int c = blockIdx.x, b = blockIdx.y;
    const int t0 = c * S;
    const int base = t0 - 151;
    const int tid = threadIdx.x;
    const int lane = tid & 63, wid = tid >> 6;
    const bool edge = (c == 0) | (c == NC - 1);
    const float* Ib = Ig + (size_t)b * Ln;
    const float* Qb = Qg + (size_t)b * Ln;

    if (!edge) {
        // interior: exact-cover unconditional staging, 5 float2 per thread;
        // paired float2 LDS stores
        const int astart = base - 1;    // even -> 8B-aligned
        const float2* I2 = reinterpret_cast<const float2*>(Ib + astart);
        const float2* Q2 = reinterpret_cast<const float2*>(Qb + astart);
        float2 vi[5], vq[5];
#pragma unroll
        for (int j = 0; j < 5; ++j) {
            int p = tid + j * TPB;      // p < NP always
            vi[j] = I2[p];
            vq[j] = Q2[p];
        }
#pragma unroll
        for (int j = 0; j < 5; ++j) {
            int p = tid + j * TPB;
            float2 vp, vm;
            vp.x = fast_atan2f(vq[j].x, vi[j].x);
            vp.y = fast_atan2f(vq[j].y, vi[j].y);
            vm.x = __builtin_amdgcn_sqrtf(__fmaf_rn(vi[j].x, vi[j].x, vq[j].x * vq[j].x));
            vm.y = __builtin_amdgcn_sqrtf(__fmaf_rn(vi[j].y, vi[j].y, vq[j].y * vq[j].y));
            reinterpret_cast<float2*>(spu_s)[p] = vp;
            reinterpret_cast<float2*>(smg_s)[p] = vm;
        }
    } else {
        // edge chunks (c==0, c==NC-1): guarded scalar staging, covers li<2560
        // (all window-read positions; li>=2560 garbage is quarantined)
#pragma unroll
        for (int j = 0; j < 10; ++j) {
            int li = tid + j * TPB;
            int g = base + li;
            float ph = 0.f, m = 0.f;
            if (g >= 0 && g < Ln) {
                float iv = Ib[g], qv = Qb[g];
                m = __builtin_amdgcn_sqrtf(__fmaf_rn(iv, iv, qv * qv));
                ph = fast_atan2f(qv, iv);
            }
            spu[li] = ph;
            smg[li] = m;
        }
    }
    __syncthreads();                                   // B1

    const int seg = tid * EPT;

    // pass 1: own segment (stride 11, conflict-free): wrap scan + mg copy/sum
    float ph[EPT], mg[EPT];
    int kloc[EPT];
    float rm = 0.f;
    {
        float prev = (tid > 0) ? spu[seg - 1] : 0.f;   // tid0: d in (-pi,pi] -> k=0
        int run = 0;
#pragma unroll
        for (int i = 0; i < EPT; ++i) {
            ph[i] = spu[seg + i];
            mg[i] = smg[seg + i];
            rm += mg[i];
            run += wrap_k(ph[i] - prev);
            kloc[i] = run;
            prev = ph[i];
        }
    }

    // combined block exclusive scan: int wrap counts + float mg sums
    int vi_ = kloc[EPT - 1];
    float vf = rm;
#pragma unroll
    for (int o = 1; o < 64; o <<= 1) {
        int ui = __shfl_up(vi_, o, 64);
        float uf = __shfl_up(vf, o, 64);
        if (lane >= o) { vi_ += ui; vf += uf; }
    }
    if (lane == 63) { iwt[wid] = vi_; fwt[wid] = vf; } // first write, no barrier needed
    __syncthreads();                                   // B3
    int addi = 0; float addf = 0.f;
#pragma unroll
    for (int w = 0; w < TPB / 64; ++w) {
        addi += (w < wid) ? iwt[w] : 0;
        addf += (w < wid) ? fwt[w] : 0.f;
    }
    const int excl = vi_ - kloc[EPT - 1] + addi;
    const float em = vf - rm + addf;

    if (tid == 13)  Ag[b * NC + c] = excl + kloc[7];   // li=150  (g=t0-1)
    if (tid == 199) Bg[b * NC + c] = excl + kloc[9];   // li=2198 (g=t0+S-1)

    // write raw pu (own segment), accumulate segment sum
    float rp = 0.f;
    if (!edge) {
#pragma unroll
        for (int i = 0; i < EPT; ++i) {
            float v = __fmaf_rn((float)(excl + kloc[i]), TWO_PI_F, ph[i]);
            rp += v;
            spu[seg + i] = v;
        }
    } else {
#pragma unroll
        for (int i = 0; i < EPT; ++i) {
            int li = seg + i;
            int g = base + li;
            float v = 0.f;
            if (g >= 0 && g < Ln)
                v = __fmaf_rn((float)(excl + kloc[i]), TWO_PI_F, ph[i]);
            rp += v;
            spu[li] = v;
        }
    }

    // block exclusive scan of pu sums; x-gathers overlapped inside barrier pair
    float incf = rp;
#pragma unroll
    for (int o = 1; o < 64; o <<= 1) {
        float uf = __shfl_up(incf, o, 64);
        if (lane >= o) incf += uf;
    }
    __syncthreads();                                   // B4 (pu visible; fwt reads done)
    if (lane == 63) fwt[wid] = incf;
    float xp[OPT], xm[OPT];
#pragma unroll
    for (int j = 0; j < OPT; ++j) {
        int lt = tid + j * TPB + 151;
        xp[j] = spu[lt];                               // raw pu (exact)
        xm[j] = smg[lt];                               // raw magnitude (exact)
    }
    __syncthreads();                                   // B5 (fwt visible; gathers done)
    float addp = 0.f;
#pragma unroll
    for (int w = 0; w < TPB / 64; ++w) addp += (w < wid) ? fwt[w] : 0.f;
    const float ep = incf - rp + addp;

    // in-place inclusive prefixes (own segment, stride-11).
    // Interior: pu recomputed from regs (bit-identical to the raw write),
    // mg from regs -> write-only LDS. Edge: guarded LDS-read path for pu.
    if (!edge) {
        float runp = ep, runm = em;
#pragma unroll
        for (int i = 0; i < EPT; ++i) {
            int li = seg + i;
            runp += __fmaf_rn((float)(excl + kloc[i]), TWO_PI_F, ph[i]);
            spu[li] = runp;
            runm += mg[i];
            smg[li] = runm;
        }
    } else {
        float runp = ep, runm = em;
#pragma unroll
        for (int i = 0; i < EPT; ++i) {
            int li = seg + i;
            runp += spu[li];
            spu[li] = runp;
            runm += mg[i];
            smg[li] = runm;
        }
    }
    __syncthreads();                                   // B6

    float s1mf = 0.f, s2mf = 0.f, s1pf = 0.f, s2pf = 0.f;
    float* om = out + ((size_t)b * 2) * Ln + t0;
    float* op = out + ((size_t)b * 2 + 1) * Ln + t0;
    constexpr float INV_K = 1.0f / 301.0f;
#pragma unroll
    for (int j = 0; j < OPT; ++j) {
        int t = tid + j * TPB;
        int lt = t + 151;
        float am = (smg[lt + 150] - smg[lt - 151]) * INV_K;
        float fm = xm[j] - am;
        float ap = (spu[lt + 150] - spu[lt - 151]) * INV_K;
        float fp = xp[j] - ap;
        om[t] = fm;
        op[t] = fp;
        s1mf += fm; s2mf = __fmaf_rn(fm, fm, s2mf);
        s1pf += fp; s2pf = __fmaf_rn(fp, fp, s2pf);
    }
    double a0 = (double)s1mf, a1 = (double)s2mf, a2 = (double)s1pf, a3 = (double)s2pf;
#pragma unroll
    for (int o = 32; o > 0; o >>= 1) {
        a0 += __shfl_down(a0, o, 64);
        a1 += __shfl_down(a1, o, 64);
        a2 += __shfl_down(a2, o, 64);
        a3 += __shfl_down(a3, o, 64);
    }
    if (lane == 0) { rbuf[wid][0] = a0; rbuf[wid][1] = a1; rbuf[wid][2] = a2; rbuf[wid][3] = a3; }
    __syncthreads();
    if (tid == 0) {
        double t0d = 0, t1d = 0, t2d = 0, t3d = 0;
#pragma unroll
        for (int w = 0; w < TPB / 64; ++w) {
            t0d += rbuf[w][0]; t1d += rbuf[w][1]; t2d += rbuf[w][2]; t3d += rbuf[w][3];
        }
        float* p = PS + (size_t)(b * NC + c) * 4;
        p[0] = (float)t0d; p[1] = (float)t1d; p[2] = (float)t2d; p[3] = (float)t3d;
    }
}

// K2: per-row: fix last-150 phase outputs (right-pad windows) + row stats.
// One wave per row.
__global__ void k_post(const int* __restrict__ Ag, const int* __restrict__ Bg,
                       float* __restrict__ out, const float* __restrict__ PS,
                       float* __restrict__ ROW) {
    const int b = blockIdx.x;
    const int lane = threadIdx.x;           // 64 threads
    const int idx = b * NC;

    // row wrap offset at chunk NC-1 start: sum W_c over c<NC-1
    int w = (Bg[idx + lane] - Ag[idx + lane]);
    if (lane + 64 < NC - 1) w += (Bg[idx + 64 + lane] - Ag[idx + 64 + lane]);
#pragma unroll
    for (int o = 32; o > 0; o >>= 1) w += __shfl_down(w, o, 64);
    int O = __shfl(w, 0, 64);
    int aL = Ag[idx + NC - 1];
    float C = TWO_PI_F * (float)(O - aL);   // pu_true - pu_prov for last chunk

    constexpr float INV_K = 1.0f / 301.0f;
    float* op = out + ((size_t)b * 2 + 1) * Ln;
    double sd = 0.0, sd2 = 0.0;
#pragma unroll
    for (int k = 0; k < 3; ++k) {
        int j = lane + k * 64;
        if (j < 150) {
            int t = Ln - 150 + j;           // npad in window = j+1
            float delta = C * (float)(j + 1) * INV_K;
            float v = op[t];
            float nv = v + delta;
            op[t] = nv;
            sd += (double)delta;
            sd2 += (double)nv * (double)nv - (double)v * (double)v;
        }
    }

    // row stats: each lane sums 2 chunks, plus its own fix deltas
    const float* p1 = PS + (size_t)(idx + lane) * 4;
    const float* p2 = PS + (size_t)(idx + 64 + lane) * 4;
    double a0 = (double)p1[0] + (double)p2[0];
    double a1 = (double)p1[1] + (double)p2[1];
    double a2 = (double)p1[2] + (double)p2[2] + sd;
    double a3 = (double)p1[3] + (double)p2[3] + sd2;
#pragma unroll
    for (int o = 32; o > 0; o >>= 1) {
        a0 += __shfl_down(a0, o, 64);
        a1 += __shfl_down(a1, o, 64);
        a2 += __shfl_down(a2, o, 64);
        a3 += __shfl_down(a3, o, 64);
    }
    if (lane == 0) {
        double Ld = (double)Ln;
        double mm = a0 / Ld;
        double vm = (a1 - a0 * a0 / Ld) / (Ld - 1.0); vm = vm > 0 ? vm : 0;
        double mp = a2 / Ld;
        double vp = (a3 - a2 * a2 / Ld) / (Ld - 1.0); vp = vp > 0 ? vp : 0;
        float* r = ROW + b * 4;
        r[0] = (float)mm;
        r[1] = (float)(1.0 / (sqrt(vm) + 1e-5));
        r[2] = (float)mp;
        r[3] = (float)(1.0 / (sqrt(vp) + 1e-5));
    }
}

// in-place normalize of d_out
__global__ __launch_bounds__(TPB) void k_norm(float* __restrict__ out,
                                              const float* __restrict__ ROW) {
    const size_t n4 = (size_t)Bn * 2 * Ln / 4;
    size_t stride = (size_t)gridDim.x * blockDim.x;
    for (size_t p4 = (size_t)blockIdx.x * blockDim.x + threadIdx.x; p4 < n4; p4 += stride) {
        size_t p = p4 * 4;
        int b = (int)(p >> 19);             // 2L = 2^19
        int sig = (int)((p >> 18) & 1);     // L = 2^18
        float mean = ROW[b * 4 + sig * 2];
        float scale = ROW[b * 4 + sig * 2 + 1];
        float4 v = reinterpret_cast<float4*>(out)[p4];
        v.x = (v.x - mean) * scale;
        v.y = (v.y - mean) * scale;
        v.z = (v.z - mean) * scale;
        v.w = (v.w - mean) * scale;
        reinterpret_cast<float4*>(out)[p4] = v;
    }
}

extern "C" void kernel_launch(void* const* d_in, const int* in_sizes, int n_in,
                              void* d_out, int out_size, void* d_ws, size_t ws_size,
                              hipStream_t stream) {
    const float* Ig = (const float*)d_in[0];
    const float* Qg = (const float*)d_in[1];
    float* out = (float*)d_out;
    char* ws = (char*)d_ws;
    int* Ag = (int*)ws;                                 // Bn*NC ints (32 KiB)
    int* Bg = (int*)(ws + 32768);                       // Bn*NC ints (32 KiB)
    float* PS = (float*)(ws + 65536);                   // Bn*NC*4 floats (128 KiB)
    float* ROW = (float*)(ws + 65536 + (size_t)Bn * NC * 4 * sizeof(float));

    dim3 grid(NC, Bn);
    hipLaunchKernelGGL(k_filt, grid, dim3(TPB), 0, stream, Ig, Qg, Ag, Bg, out, PS);
    hipLaunchKernelGGL(k_post, dim3(Bn), dim3(64), 0, stream, Ag, Bg, out, PS, ROW);
    hipLaunchKernelGGL(k_norm, dim3(4096), dim3(TPB), 0, stream, out, ROW);
}

// Round 12
// 100.196 us; speedup vs baseline: 1.2550x; 1.2550x over previous
//
#include <hip/hip_runtime.h>
#include <math.h>

#define TPB 256
constexpr int Bn = 64;
constexpr int Ln = 262144;          // 2^18
constexpr int S  = 2048;            // chunk/tile size
constexpr int NC = Ln / S;          // 128 chunks per row
constexpr int HA = S + 301;         // halo'd extent (2349)
constexpr int EPT = 11;             // segment length; ODD stride -> conflict-free LDS
constexpr int OPT = S / TPB;        // 8 outputs per thread
constexpr int NP = 1280;            // float2 pairs staged (2560 floats, li in [-1,2559))
constexpr int LDSZ = 2820;          // 1 (shift) + 11*256=2816 coverage + pad

constexpr float TWO_PI_F = 6.28318530717958647692f;
constexpr float PI_F = 3.14159265358979323846f;
constexpr float HALF_PI_F = 1.57079632679489661923f;
constexpr float INV_TWO_PI_F = 0.15915494309189533577f;

// wrap count: k = floor((d+pi)/(2pi)), with the reference's dm==-pi & d>0 fixup.
__device__ __forceinline__ int wrap_k(float d) {
    float kf = floorf(__fmaf_rn(d, INV_TWO_PI_F, 0.5f));
    float dm = __fmaf_rn(-kf, TWO_PI_F, d);
    if (dm == -PI_F && d > 0.f) kf -= 1.f;
    return (int)kf;
}

// polynomial atan2, abs err ~2e-7 rad
__device__ __forceinline__ float fast_atan2f(float q, float i) {
    float aq = fabsf(q), ai = fabsf(i);
    float mx = fmaxf(aq, ai), mn = fminf(aq, ai);
    float r = __builtin_amdgcn_rcpf(mx);
    r = r * (2.0f - mx * r);                 // one NR step
    float t = mn * r;                        // in [0, 1+eps]
    if (mx == 0.f) t = 0.f;                  // atan2(0,0) -> 0
    float s = t * t;
    float p = __fmaf_rn(s, 0.0028662257f, -0.0161657367f);
    p = __fmaf_rn(p, s,  0.0429096138f);
    p = __fmaf_rn(p, s, -0.0752896400f);
    p = __fmaf_rn(p, s,  0.1065626393f);
    p = __fmaf_rn(p, s, -0.1420889944f);
    p = __fmaf_rn(p, s,  0.1999355085f);
    p = __fmaf_rn(p, s, -0.3333314528f);
    float at = __fmaf_rn(p * s, t, t);       // t + t*s*poly
    if (aq > ai) at = HALF_PI_F - at;
    if (i < 0.f) at = PI_F - at;
    return (q < 0.f) ? -at : at;
}

// K1: locally-anchored unwrap + moving-average high-pass.
// LDS holds only the two INCLUSIVE PREFIX arrays after construction; raw
// values are recovered by differencing (P[t]-P[t-1]) -> no raw-pu write,
// no x-gather phase.
__global__ __launch_bounds__(TPB, 7) void k_filt(const float* __restrict__ Ig,
                                                 const float* __restrict__ Qg,
                                                 int* __restrict__ Ag,     // local scan at g=t0-1
                                                 int* __restrict__ Bg,     // local scan at g=t0+S-1
                                                 float* __restrict__ out,
                                                 float* __restrict__ PS) {
    __shared__ __align__(16) float spu_s[LDSZ];   // phase -> prefix(pu)
    __shared__ __align__(16) float smg_s[LDSZ];   // magnitude -> prefix(magnitude)
    __shared__ int iwt[TPB / 64];
    __shared__ float fwt[TPB / 64];
    __shared__ float fwt2[TPB / 64];
    __shared__ float rbuf[TPB / 64][4];
    float* spu = spu_s + 1;             // logical li -> spu[li]
    float* smg = smg_s + 1;

    const int c = blockIdx.x, b = blockIdx.y;
    const int t0 = c * S;
    const int base = t0 - 151;
    const int tid = threadIdx.x;
    const int lane = tid & 63, wid = tid >> 6;
    const bool edge = (c == 0) | (c == NC - 1);
    const float* Ib = Ig + (size_t)b * Ln;
    const float* Qb = Qg + (size_t)b * Ln;

    if (!edge) {
        // interior: exact-cover unconditional staging, 5 float2 per thread
        const int astart = base - 1;    // even -> 8B-aligned
        const float2* I2 = reinterpret_cast<const float2*>(Ib + astart);
        const float2* Q2 = reinterpret_cast<const float2*>(Qb + astart);
        float2 vi[5], vq[5];
#pragma unroll
        for (int j = 0; j < 5; ++j) {
            int p = tid + j * TPB;      // p < NP always
            vi[j] = I2[p];
            vq[j] = Q2[p];
        }
#pragma unroll
        for (int j = 0; j < 5; ++j) {
            int p = tid + j * TPB;
            float2 vp, vm;
            vp.x = fast_atan2f(vq[j].x, vi[j].x);
            vp.y = fast_atan2f(vq[j].y, vi[j].y);
            vm.x = __builtin_amdgcn_sqrtf(__fmaf_rn(vi[j].x, vi[j].x, vq[j].x * vq[j].x));
            vm.y = __builtin_amdgcn_sqrtf(__fmaf_rn(vi[j].y, vi[j].y, vq[j].y * vq[j].y));
            reinterpret_cast<float2*>(spu_s)[p] = vp;
            reinterpret_cast<float2*>(smg_s)[p] = vm;
        }
    } else {
        // edge chunks (c==0, c==NC-1): guarded scalar staging, covers li<2560
#pragma unroll
        for (int j = 0; j < 10; ++j) {
            int li = tid + j * TPB;
            int g = base + li;
            float ph = 0.f, m = 0.f;
            if (g >= 0 && g < Ln) {
                float iv = Ib[g], qv = Qb[g];
                m = __builtin_amdgcn_sqrtf(__fmaf_rn(iv, iv, qv * qv));
                ph = fast_atan2f(qv, iv);
            }
            spu[li] = ph;
            smg[li] = m;
        }
    }
    __syncthreads();                                   // B1

    const int seg = tid * EPT;

    // pass 1: own segment (stride 11, conflict-free): wrap scan + mg sum
    float ph[EPT];
    int kloc[EPT];
    float rm = 0.f;
    {
        float prev = (tid > 0) ? spu[seg - 1] : 0.f;   // tid0: d in (-pi,pi] -> k=0
        int run = 0;
#pragma unroll
        for (int i = 0; i < EPT; ++i) {
            ph[i] = spu[seg + i];
            rm += smg[seg + i];
            run += wrap_k(ph[i] - prev);
            kloc[i] = run;
            prev = ph[i];
        }
    }

    // combined block exclusive scan: int wrap counts + float mg sums
    int vi_ = kloc[EPT - 1];
    float vf = rm;
#pragma unroll
    for (int o = 1; o < 64; o <<= 1) {
        int ui = __shfl_up(vi_, o, 64);
        float uf = __shfl_up(vf, o, 64);
        if (lane >= o) { vi_ += ui; vf += uf; }
    }
    if (lane == 63) { iwt[wid] = vi_; fwt[wid] = vf; } // first write, no barrier needed
    __syncthreads();                                   // B2
    int addi = 0; float addf = 0.f;
#pragma unroll
    for (int w = 0; w < TPB / 64; ++w) {
        addi += (w < wid) ? iwt[w] : 0;
        addf += (w < wid) ? fwt[w] : 0.f;
    }
    const int excl = vi_ - kloc[EPT - 1] + addi;
    const float em = vf - rm + addf;

    if (tid == 13)  Ag[b * NC + c] = excl + kloc[7];   // li=150  (g=t0-1)
    if (tid == 199) Bg[b * NC + c] = excl + kloc[9];   // li=2198 (g=t0+S-1)

    // pu segment sum from registers (no LDS write of raw pu)
    float rp = 0.f;
    if (!edge) {
#pragma unroll
        for (int i = 0; i < EPT; ++i)
            rp += __fmaf_rn((float)(excl + kloc[i]), TWO_PI_F, ph[i]);
    } else {
#pragma unroll
        for (int i = 0; i < EPT; ++i) {
            int g = base + seg + i;
            if (g >= 0 && g < Ln)
                rp += __fmaf_rn((float)(excl + kloc[i]), TWO_PI_F, ph[i]);
        }
    }

    // block exclusive scan of pu sums (separate buffer -> no WAR barrier)
    float incf = rp;
#pragma unroll
    for (int o = 1; o < 64; o <<= 1) {
        float uf = __shfl_up(incf, o, 64);
        if (lane >= o) incf += uf;
    }
    if (lane == 63) fwt2[wid] = incf;
    __syncthreads();                                   // B3 (fwt2 visible; pass-1 reads done)
    float addp = 0.f;
#pragma unroll
    for (int w = 0; w < TPB / 64; ++w) addp += (w < wid) ? fwt2[w] : 0.f;
    const float ep = incf - rp + addp;

    // write inclusive prefixes: pu from regs (write-only), mg RMW (stride-11)
    if (!edge) {
        float runp = ep, runm = em;
#pragma unroll
        for (int i = 0; i < EPT; ++i) {
            int li = seg + i;
            runp += __fmaf_rn((float)(excl + kloc[i]), TWO_PI_F, ph[i]);
            spu[li] = runp;
            runm += smg[li];
            smg[li] = runm;
        }
    } else {
        float runp = ep, runm = em;
#pragma unroll
        for (int i = 0; i < EPT; ++i) {
            int li = seg + i;
            int g = base + li;
            float v = 0.f;
            if (g >= 0 && g < Ln)
                v = __fmaf_rn((float)(excl + kloc[i]), TWO_PI_F, ph[i]);
            runp += v;
            spu[li] = runp;
            runm += smg[li];
            smg[li] = runm;
        }
    }
    __syncthreads();                                   // B4

    float s1mf = 0.f, s2mf = 0.f, s1pf = 0.f, s2pf = 0.f;
    float* om = out + ((size_t)b * 2) * Ln + t0;
    float* op = out + ((size_t)b * 2 + 1) * Ln + t0;
    constexpr float INV_K = 1.0f / 301.0f;
#pragma unroll
    for (int j = 0; j < OPT; ++j) {
        int t = tid + j * TPB;
        int lt = t + 151;
        float Mq = smg[lt - 151], Mm = smg[lt - 1], Ml = smg[lt], Mp = smg[lt + 150];
        float Pq = spu[lt - 151], Pm = spu[lt - 1], Pl = spu[lt], Pp = spu[lt + 150];
        float fm = (Ml - Mm) - (Mp - Mq) * INV_K;
        float fp = (Pl - Pm) - (Pp - Pq) * INV_K;
        om[t] = fm;
        op[t] = fp;
        s1mf += fm; s2mf = __fmaf_rn(fm, fm, s2mf);
        s1pf += fp; s2pf = __fmaf_rn(fp, fp, s2pf);
    }
    // f32 wave reduce (halves bpermute count vs doubles)
#pragma unroll
    for (int o = 32; o > 0; o >>= 1) {
        s1mf += __shfl_down(s1mf, o, 64);
        s2mf += __shfl_down(s2mf, o, 64);
        s1pf += __shfl_down(s1pf, o, 64);
        s2pf += __shfl_down(s2pf, o, 64);
    }
    if (lane == 0) { rbuf[wid][0] = s1mf; rbuf[wid][1] = s2mf; rbuf[wid][2] = s1pf; rbuf[wid][3] = s2pf; }
    __syncthreads();                                   // B5
    if (tid == 0) {
        float t0f = 0.f, t1f = 0.f, t2f = 0.f, t3f = 0.f;
#pragma unroll
        for (int w = 0; w < TPB / 64; ++w) {
            t0f += rbuf[w][0]; t1f += rbuf[w][1]; t2f += rbuf[w][2]; t3f += rbuf[w][3];
        }
        float* p = PS + (size_t)(b * NC + c) * 4;
        p[0] = t0f; p[1] = t1f; p[2] = t2f; p[3] = t3f;
    }
}

// K2: per-row: fix last-150 phase outputs (right-pad windows) + row stats.
// One wave per row.
__global__ void k_post(const int* __restrict__ Ag, const int* __restrict__ Bg,
                       float* __restrict__ out, const float* __restrict__ PS,
                       float* __restrict__ ROW) {
    const int b = blockIdx.x;
    const int lane = threadIdx.x;           // 64 threads
    const int idx = b * NC;

    // row wrap offset at chunk NC-1 start: sum W_c over c<NC-1
    int w = (Bg[idx + lane] - Ag[idx + lane]);
    if (lane + 64 < NC - 1) w += (Bg[idx + 64 + lane] - Ag[idx + 64 + lane]);
#pragma unroll
    for (int o = 32; o > 0; o >>= 1) w += __shfl_down(w, o, 64);
    int O = __shfl(w, 0, 64);
    int aL = Ag[idx + NC - 1];
    float C = TWO_PI_F * (float)(O - aL);   // pu_true - pu_prov for last chunk

    constexpr float INV_K = 1.0f / 301.0f;
    float* op = out + ((size_t)b * 2 + 1) * Ln;
    double sd = 0.0, sd2 = 0.0;
#pragma unroll
    for (int k = 0; k < 3; ++k) {
        int j = lane + k * 64;
        if (j < 150) {
            int t = Ln - 150 + j;           // npad in window = j+1
            float delta = C * (float)(j + 1) * INV_K;
            float v = op[t];
            float nv = v + delta;
            op[t] = nv;
            sd += (double)delta;
            sd2 += (double)nv * (double)nv - (double)v * (double)v;
        }
    }

    // row stats: each lane sums 2 chunks, plus its own fix deltas
    const float* p1 = PS + (size_t)(idx + lane) * 4;
    const float* p2 = PS + (size_t)(idx + 64 + lane) * 4;
    double a0 = (double)p1[0] + (double)p2[0];
    double a1 = (double)p1[1] + (double)p2[1];
    double a2 = (double)p1[2] + (double)p2[2] + sd;
    double a3 = (double)p1[3] + (double)p2[3] + sd2;
#pragma unroll
    for (int o = 32; o > 0; o >>= 1) {
        a0 += __shfl_down(a0, o, 64);
        a1 += __shfl_down(a1, o, 64);
        a2 += __shfl_down(a2, o, 64);
        a3 += __shfl_down(a3, o, 64);
    }
    if (lane == 0) {
        double Ld = (double)Ln;
        double mm = a0 / Ld;
        double vm = (a1 - a0 * a0 / Ld) / (Ld - 1.0); vm = vm > 0 ? vm : 0;
        double mp = a2 / Ld;
        double vp = (a3 - a2 * a2 / Ld) / (Ld - 1.0); vp = vp > 0 ? vp : 0;
        float* r = ROW + b * 4;
        r[0] = (float)mm;
        r[1] = (float)(1.0 / (sqrt(vm) + 1e-5));
        r[2] = (float)mp;
        r[3] = (float)(1.0 / (sqrt(vp) + 1e-5));
    }
}

// in-place normalize of d_out
__global__ __launch_bounds__(TPB) void k_norm(float* __restrict__ out,
                                              const float* __restrict__ ROW) {
    const size_t n4 = (size_t)Bn * 2 * Ln / 4;
    size_t stride = (size_t)gridDim.x * blockDim.x;
    for (size_t p4 = (size_t)blockIdx.x * blockDim.x + threadIdx.x; p4 < n4; p4 += stride) {
        size_t p = p4 * 4;
        int b = (int)(p >> 19);             // 2L = 2^19
        int sig = (int)((p >> 18) & 1);     // L = 2^18
        float mean = ROW[b * 4 + sig * 2];
        float scale = ROW[b * 4 + sig * 2 + 1];
        float4 v = reinterpret_cast<float4*>(out)[p4];
        v.x = (v.x - mean) * scale;
        v.y = (v.y - mean) * scale;
        v.z = (v.z - mean) * scale;
        v.w = (v.w - mean) * scale;
        reinterpret_cast<float4*>(out)[p4] = v;
    }
}

extern "C" void kernel_launch(void* const* d_in, const int* in_sizes, int n_in,
                              void* d_out, int out_size, void* d_ws, size_t ws_size,
                              hipStream_t stream) {
    const float* Ig = (const float*)d_in[0];
    const float* Qg = (const float*)d_in[1];
    float* out = (float*)d_out;
    char* ws = (char*)d_ws;
    int* Ag = (int*)ws;                                 // Bn*NC ints (32 KiB)
    int* Bg = (int*)(ws + 32768);                       // Bn*NC ints (32 KiB)
    float* PS = (float*)(ws + 65536);                   // Bn*NC*4 floats (128 KiB)
    float* ROW = (float*)(ws + 65536 + (size_t)Bn * NC * 4 * sizeof(float));

    dim3 grid(NC, Bn);
    hipLaunchKernelGGL(k_filt, grid, dim3(TPB), 0, stream, Ig, Qg, Ag, Bg, out, PS);
    hipLaunchKernelGGL(k_post, dim3(Bn), dim3(64), 0, stream, Ag, Bg, out, PS, ROW);
    hipLaunchKernelGGL(k_norm, dim3(4096), dim3(TPB), 0, stream, out, ROW);
}

// Round 13
// 99.925 us; speedup vs baseline: 1.2584x; 1.0027x over previous
//
#include <hip/hip_runtime.h>
#include <math.h>

#define TPB 512
constexpr int Bn = 64;
constexpr int Ln = 262144;          // 2^18
constexpr int S  = 4096;            // chunk/tile size
constexpr int NC = Ln / S;          // 64 chunks per row
constexpr int HA = S + 301;         // halo'd extent (4397)
constexpr int EPT = 9;              // segment length; ODD -> conflict-free LDS
constexpr int OPT = S / TPB;        // 8 outputs per thread
constexpr int NP = 2306;            // float2 pairs staged (4612 floats, li in [-1,4611))
constexpr int LDSZ = 4612;          // spu_s[0..4611]; coverage 1+4608+3
constexpr int NW = TPB / 64;        // 8 waves

constexpr float TWO_PI_F = 6.28318530717958647692f;
constexpr float PI_F = 3.14159265358979323846f;
constexpr float HALF_PI_F = 1.57079632679489661923f;
constexpr float INV_TWO_PI_F = 0.15915494309189533577f;

// wrap count: k = floor((d+pi)/(2pi)), with the reference's dm==-pi & d>0 fixup.
__device__ __forceinline__ int wrap_k(float d) {
    float kf = floorf(__fmaf_rn(d, INV_TWO_PI_F, 0.5f));
    float dm = __fmaf_rn(-kf, TWO_PI_F, d);
    if (dm == -PI_F && d > 0.f) kf -= 1.f;
    return (int)kf;
}

// polynomial atan2, abs err ~2e-7 rad
__device__ __forceinline__ float fast_atan2f(float q, float i) {
    float aq = fabsf(q), ai = fabsf(i);
    float mx = fmaxf(aq, ai), mn = fminf(aq, ai);
    float r = __builtin_amdgcn_rcpf(mx);
    r = r * (2.0f - mx * r);                 // one NR step
    float t = mn * r;                        // in [0, 1+eps]
    if (mx == 0.f) t = 0.f;                  // atan2(0,0) -> 0
    float s = t * t;
    float p = __fmaf_rn(s, 0.0028662257f, -0.0161657367f);
    p = __fmaf_rn(p, s,  0.0429096138f);
    p = __fmaf_rn(p, s, -0.0752896400f);
    p = __fmaf_rn(p, s,  0.1065626393f);
    p = __fmaf_rn(p, s, -0.1420889944f);
    p = __fmaf_rn(p, s,  0.1999355085f);
    p = __fmaf_rn(p, s, -0.3333314528f);
    float at = __fmaf_rn(p * s, t, t);       // t + t*s*poly
    if (aq > ai) at = HALF_PI_F - at;
    if (i < 0.f) at = PI_F - at;
    return (q < 0.f) ? -at : at;
}

// K1: locally-anchored unwrap + moving-average high-pass. LDS holds only the
// two inclusive-prefix arrays; raw values recovered by differencing.
__global__ __launch_bounds__(TPB, 8) void k_filt(const float* __restrict__ Ig,
                                                 const float* __restrict__ Qg,
                                                 int* __restrict__ Ag,     // local scan at g=t0-1
                                                 int* __restrict__ Bg,     // local scan at g=t0+S-1
                                                 float* __restrict__ out,
                                                 float* __restrict__ PS) {
    __shared__ __align__(16) float spu_s[LDSZ];   // phase -> prefix(pu)
    __shared__ __align__(16) float smg_s[LDSZ];   // magnitude -> prefix(magnitude)
    __shared__ int iwt[NW];
    __shared__ float fwt[NW];
    __shared__ float fwt2[NW];
    __shared__ float rbuf[NW][4];
    float* spu = spu_s + 1;             // logical li -> spu[li]
    float* smg = smg_s + 1;

    const int c = blockIdx.x, b = blockIdx.y;
    const int t0 = c * S;
    const int base = t0 - 151;
    const int tid = threadIdx.x;
    const int lane = tid & 63, wid = tid >> 6;
    const bool edge = (c == 0) | (c == NC - 1);
    const float* Ib = Ig + (size_t)b * Ln;
    const float* Qb = Qg + (size_t)b * Ln;

    if (!edge) {
        // interior: float2 staging covering spu_s[0..4611] (g in [t0-152, t0+4460))
        const int astart = base - 1;    // even -> 8B-aligned
        const float2* I2 = reinterpret_cast<const float2*>(Ib + astart);
        const float2* Q2 = reinterpret_cast<const float2*>(Qb + astart);
        float2 vi[5], vq[5];
#pragma unroll
        for (int j = 0; j < 5; ++j) {
            int p = tid + j * TPB;
            if (p < NP) { vi[j] = I2[p]; vq[j] = Q2[p]; }
        }
#pragma unroll
        for (int j = 0; j < 5; ++j) {
            int p = tid + j * TPB;
            if (p < NP) {
                float2 vp, vm;
                vp.x = fast_atan2f(vq[j].x, vi[j].x);
                vp.y = fast_atan2f(vq[j].y, vi[j].y);
                vm.x = __builtin_amdgcn_sqrtf(__fmaf_rn(vi[j].x, vi[j].x, vq[j].x * vq[j].x));
                vm.y = __builtin_amdgcn_sqrtf(__fmaf_rn(vi[j].y, vi[j].y, vq[j].y * vq[j].y));
                reinterpret_cast<float2*>(spu_s)[p] = vp;
                reinterpret_cast<float2*>(smg_s)[p] = vm;
            }
        }
    } else {
        // edge chunks (c==0, c==NC-1): guarded scalar staging, li 0..4607
        // (spu_s[0] never read; all read positions <= li 4396 covered)
#pragma unroll
        for (int j = 0; j < 9; ++j) {
            int li = tid + j * TPB;
            int g = base + li;
            float ph = 0.f, m = 0.f;
            if (g >= 0 && g < Ln) {
                float iv = Ib[g], qv = Qb[g];
                m = __builtin_amdgcn_sqrtf(__fmaf_rn(iv, iv, qv * qv));
                ph = fast_atan2f(qv, iv);
            }
            spu[li] = ph;
            smg[li] = m;
        }
    }
    __syncthreads();                                   // B1

    const int seg = tid * EPT;

    // pass 1: own segment (stride 9, conflict-free): wrap scan + mg->regs
    float ph[EPT], mg[EPT];
    int kloc[EPT];
    float rm = 0.f;
    {
        float prev = (tid > 0) ? spu[seg - 1] : 0.f;   // tid0: |d|<=pi -> k=0
        int run = 0;
#pragma unroll
        for (int i = 0; i < EPT; ++i) {
            ph[i] = spu[seg + i];
            mg[i] = smg[seg + i];
            rm += mg[i];
            run += wrap_k(ph[i] - prev);
            kloc[i] = run;
            prev = ph[i];
        }
    }

    // combined block exclusive scan: int wrap counts + float mg sums
    int vi_ = kloc[EPT - 1];
    float vf = rm;
#pragma unroll
    for (int o = 1; o < 64; o <<= 1) {
        int ui = __shfl_up(vi_, o, 64);
        float uf = __shfl_up(vf, o, 64);
        if (lane >= o) { vi_ += ui; vf += uf; }
    }
    if (lane == 63) { iwt[wid] = vi_; fwt[wid] = vf; }
    __syncthreads();                                   // B2
    int addi = 0; float addf = 0.f;
#pragma unroll
    for (int w = 0; w < NW; ++w) {
        addi += (w < wid) ? iwt[w] : 0;
        addf += (w < wid) ? fwt[w] : 0.f;
    }
    const int excl = vi_ - kloc[EPT - 1] + addi;
    const float em = vf - rm + addf;

    if (tid == 16)  Ag[b * NC + c] = excl + kloc[6];   // li=150  (g=t0-1)
    if (tid == 471) Bg[b * NC + c] = excl + kloc[7];   // li=4246 (g=t0+S-1)

    // pu segment sum from registers (no raw-pu LDS write)
    float rp = 0.f;
    if (!edge) {
#pragma unroll
        for (int i = 0; i < EPT; ++i)
            rp += __fmaf_rn((float)(excl + kloc[i]), TWO_PI_F, ph[i]);
    } else {
#pragma unroll
        for (int i = 0; i < EPT; ++i) {
            int g = base + seg + i;
            if (g >= 0 && g < Ln)
                rp += __fmaf_rn((float)(excl + kloc[i]), TWO_PI_F, ph[i]);
        }
    }

    // block exclusive scan of pu sums (separate buffer -> no WAR barrier)
    float incf = rp;
#pragma unroll
    for (int o = 1; o < 64; o <<= 1) {
        float uf = __shfl_up(incf, o, 64);
        if (lane >= o) incf += uf;
    }
    if (lane == 63) fwt2[wid] = incf;
    __syncthreads();                                   // B3
    float addp = 0.f;
#pragma unroll
    for (int w = 0; w < NW; ++w) addp += (w < wid) ? fwt2[w] : 0.f;
    const float ep = incf - rp + addp;

    // write inclusive prefixes from registers (both arrays write-only)
    if (!edge) {
        float runp = ep, runm = em;
#pragma unroll
        for (int i = 0; i < EPT; ++i) {
            int li = seg + i;
            runp += __fmaf_rn((float)(excl + kloc[i]), TWO_PI_F, ph[i]);
            spu[li] = runp;
            runm += mg[i];
            smg[li] = runm;
        }
    } else {
        float runp = ep, runm = em;
#pragma unroll
        for (int i = 0; i < EPT; ++i) {
            int li = seg + i;
            int g = base + li;
            float v = 0.f;
            if (g >= 0 && g < Ln)
                v = __fmaf_rn((float)(excl + kloc[i]), TWO_PI_F, ph[i]);
            runp += v;
            spu[li] = runp;
            runm += mg[i];
            smg[li] = runm;
        }
    }
    __syncthreads();                                   // B4

    float s1mf = 0.f, s2mf = 0.f, s1pf = 0.f, s2pf = 0.f;
    float* om = out + ((size_t)b * 2) * Ln + t0;
    float* op = out + ((size_t)b * 2 + 1) * Ln + t0;
    constexpr float INV_K = 1.0f / 301.0f;
#pragma unroll
    for (int j = 0; j < OPT; ++j) {
        int t = tid + j * TPB;
        int lt = t + 151;
        float Mq = smg[lt - 151], Mm = smg[lt - 1], Ml = smg[lt], Mp = smg[lt + 150];
        float Pq = spu[lt - 151], Pm = spu[lt - 1], Pl = spu[lt], Pp = spu[lt + 150];
        float fm = (Ml - Mm) - (Mp - Mq) * INV_K;
        float fp = (Pl - Pm) - (Pp - Pq) * INV_K;
        om[t] = fm;
        op[t] = fp;
        s1mf += fm; s2mf = __fmaf_rn(fm, fm, s2mf);
        s1pf += fp; s2pf = __fmaf_rn(fp, fp, s2pf);
    }
    // f32 wave reduce
#pragma unroll
    for (int o = 32; o > 0; o >>= 1) {
        s1mf += __shfl_down(s1mf, o, 64);
        s2mf += __shfl_down(s2mf, o, 64);
        s1pf += __shfl_down(s1pf, o, 64);
        s2pf += __shfl_down(s2pf, o, 64);
    }
    if (lane == 0) { rbuf[wid][0] = s1mf; rbuf[wid][1] = s2mf; rbuf[wid][2] = s1pf; rbuf[wid][3] = s2pf; }
    __syncthreads();                                   // B5
    if (tid == 0) {
        float t0f = 0.f, t1f = 0.f, t2f = 0.f, t3f = 0.f;
#pragma unroll
        for (int w = 0; w < NW; ++w) {
            t0f += rbuf[w][0]; t1f += rbuf[w][1]; t2f += rbuf[w][2]; t3f += rbuf[w][3];
        }
        float* p = PS + (size_t)(b * NC + c) * 4;
        p[0] = t0f; p[1] = t1f; p[2] = t2f; p[3] = t3f;
    }
}

// K2: per-row: fix last-150 phase outputs (right-pad windows) + row stats.
// One wave per row; NC==64 -> one chunk per lane.
__global__ void k_post(const int* __restrict__ Ag, const int* __restrict__ Bg,
                       float* __restrict__ out, const float* __restrict__ PS,
                       float* __restrict__ ROW) {
    const int b = blockIdx.x;
    const int lane = threadIdx.x;           // 64 threads
    const int idx = b * NC;

    int a = Ag[idx + lane];
    int bb = Bg[idx + lane];
    int aL = __shfl(a, 63, 64);
    int w = (lane < 63) ? (bb - a) : 0;     // chunk wrap sums W_c
#pragma unroll
    for (int o = 32; o > 0; o >>= 1) w += __shfl_down(w, o, 64);
    int O = __shfl(w, 0, 64);               // row wrap offset at chunk 63 start
    float C = TWO_PI_F * (float)(O - aL);   // pu_true - pu_prov for last chunk

    constexpr float INV_K = 1.0f / 301.0f;
    float* op = out + ((size_t)b * 2 + 1) * Ln;
    double sd = 0.0, sd2 = 0.0;
#pragma unroll
    for (int k = 0; k < 3; ++k) {
        int j = lane + k * 64;
        if (j < 150) {
            int t = Ln - 150 + j;           // npad in window = j+1
            float delta = C * (float)(j + 1) * INV_K;
            float v = op[t];
            float nv = v + delta;
            op[t] = nv;
            sd += (double)delta;
            sd2 += (double)nv * (double)nv - (double)v * (double)v;
        }
    }

    // row stats: one chunk per lane, plus fix deltas
    const float* p1 = PS + (size_t)(idx + lane) * 4;
    double a0 = (double)p1[0];
    double a1 = (double)p1[1];
    double a2 = (double)p1[2] + sd;
    double a3 = (double)p1[3] + sd2;
#pragma unroll
    for (int o = 32; o > 0; o >>= 1) {
        a0 += __shfl_down(a0, o, 64);
        a1 += __shfl_down(a1, o, 64);
        a2 += __shfl_down(a2, o, 64);
        a3 += __shfl_down(a3, o, 64);
    }
    if (lane == 0) {
        double Ld = (double)Ln;
        double mm = a0 / Ld;
        double vm = (a1 - a0 * a0 / Ld) / (Ld - 1.0); vm = vm > 0 ? vm : 0;
        double mp = a2 / Ld;
        double vp = (a3 - a2 * a2 / Ld) / (Ld - 1.0); vp = vp > 0 ? vp : 0;
        float* r = ROW + b * 4;
        r[0] = (float)mm;
        r[1] = (float)(1.0 / (sqrt(vm) + 1e-5));
        r[2] = (float)mp;
        r[3] = (float)(1.0 / (sqrt(vp) + 1e-5));
    }
}

// in-place normalize of d_out
__global__ __launch_bounds__(256) void k_norm(float* __restrict__ out,
                                              const float* __restrict__ ROW) {
    const size_t n4 = (size_t)Bn * 2 * Ln / 4;
    size_t stride = (size_t)gridDim.x * blockDim.x;
    for (size_t p4 = (size_t)blockIdx.x * blockDim.x + threadIdx.x; p4 < n4; p4 += stride) {
        size_t p = p4 * 4;
        int b = (int)(p >> 19);             // 2L = 2^19
        int sig = (int)((p >> 18) & 1);     // L = 2^18
        float mean = ROW[b * 4 + sig * 2];
        float scale = ROW[b * 4 + sig * 2 + 1];
        float4 v = reinterpret_cast<float4*>(out)[p4];
        v.x = (v.x - mean) * scale;
        v.y = (v.y - mean) * scale;
        v.z = (v.z - mean) * scale;
        v.w = (v.w - mean) * scale;
        reinterpret_cast<float4*>(out)[p4] = v;
    }
}

extern "C" void kernel_launch(void* const* d_in, const int* in_sizes, int n_in,
                              void* d_out, int out_size, void* d_ws, size_t ws_size,
                              hipStream_t stream) {
    const float* Ig = (const float*)d_in[0];
    const float* Qg = (const float*)d_in[1];
    float* out = (float*)d_out;
    char* ws = (char*)d_ws;
    int* Ag = (int*)ws;                                 // Bn*NC ints (16 KiB)
    int* Bg = (int*)(ws + 16384);                       // Bn*NC ints (16 KiB)
    float* PS = (float*)(ws + 32768);                   // Bn*NC*4 floats (64 KiB)
    float* ROW = (float*)(ws + 32768 + (size_t)Bn * NC * 4 * sizeof(float));

    dim3 grid(NC, Bn);
    hipLaunchKernelGGL(k_filt, grid, dim3(TPB), 0, stream, Ig, Qg, Ag, Bg, out, PS);
    hipLaunchKernelGGL(k_post, dim3(Bn), dim3(64), 0, stream, Ag, Bg, out, PS, ROW);
    hipLaunchKernelGGL(k_norm, dim3(4096), dim3(256), 0, stream, out, ROW);
}